// Round 6
// baseline (485.713 us; speedup 1.0000x reference)
//
#include <hip/hip_runtime.h>

// ---------- common ----------
typedef __bf16 bfv8 __attribute__((ext_vector_type(8)));
typedef float f32x4 __attribute__((ext_vector_type(4)));

#define DMODEL 2048
#define NHEADS 16
#define HEADD 128
#define SEQ 2048
#define BATCH 2
#define MROWS (BATCH * SEQ)   // 4096

__device__ __forceinline__ unsigned short f2bf(float f) {
    unsigned int x = __float_as_uint(f);
    x += 0x7fffu + ((x >> 16) & 1u);   // round-to-nearest-even
    return (unsigned short)(x >> 16);
}
__device__ __forceinline__ unsigned int pk2(float a, float b) {
    return (unsigned int)f2bf(a) | ((unsigned int)f2bf(b) << 16);
}

// ---------- fused fp32 -> bf16 convert for x + 4 weights (dst contiguous in ws) ----------
__global__ __launch_bounds__(256) void cvt_all(const float* __restrict__ x,
                                               const float* __restrict__ wq,
                                               const float* __restrict__ wk,
                                               const float* __restrict__ wv,
                                               const float* __restrict__ wo,
                                               unsigned short* __restrict__ dst) {
    int bid = blockIdx.x;
    const float* s;
    int off;
    if (bid < 8192)       { s = x;  off = bid; }
    else if (bid < 12288) { s = wq; off = bid - 8192; }
    else if (bid < 16384) { s = wk; off = bid - 12288; }
    else if (bid < 20480) { s = wv; off = bid - 16384; }
    else                  { s = wo; off = bid - 20480; }
    int i = off * 1024 + threadIdx.x * 4;
    float4 v = *(const float4*)(s + i);
    ushort4 o;
    o.x = f2bf(v.x); o.y = f2bf(v.y); o.z = f2bf(v.z); o.w = f2bf(v.w);
    *(ushort4*)(dst + (size_t)bid * 1024 + threadIdx.x * 4) = o;
}

// ============================================================
// global_load_lds staging into XOR-swizzled unpadded LDS.
// CPRL = log2(16B-chunks per row). Stored chunk c holds global
// chunk g = c ^ (row & 7).
// ============================================================
template <int CPRL, int ITERS>
__device__ __forceinline__ void stage_n(const unsigned short* __restrict__ gbase,
                                        unsigned short* lds, size_t strideShorts,
                                        int wave, int lane) {
#pragma unroll
    for (int i = 0; i < ITERS; ++i) {
        int L = wave * (64 * ITERS) + i * 64 + lane;
        int m = L >> CPRL, c = L & ((1 << CPRL) - 1);
        int g = c ^ (m & 7);
        const unsigned short* gp = gbase + (size_t)m * strideShorts + g * 8;
        __builtin_amdgcn_global_load_lds(
            (const __attribute__((address_space(1))) unsigned int*)gp,
            (__attribute__((address_space(3))) unsigned int*)(lds + (size_t)(wave * (64 * ITERS) + i * 64) * 8),
            16, 0, 0);
    }
}

#define GBK 64

// ---------- fused QKV GEMM + RoPE + per-head LN epilogue ----------
// A[4096][2048] x Wcat[6144][2048]^T; region 0 -> Q bf16 (rope+LN+scale),
// 1 -> K bf16 (rope+LN), 2 -> V bf16 transposed per head
// NOTE: no min-waves arg — (256,4) capped VGPR at 64 and spilled the
// accumulators to scratch (round-5 profile: WRITE_SIZE 50->130 MB).
__global__ __launch_bounds__(256) void gemm_qkv(const unsigned short* __restrict__ A,
                                                const unsigned short* __restrict__ Bw,
                                                unsigned short* __restrict__ Qb,
                                                unsigned short* __restrict__ Kb,
                                                unsigned short* __restrict__ VT,
                                                const float* __restrict__ qnw,
                                                const float* __restrict__ knw) {
    __shared__ __align__(16) unsigned short As[128 * 64];
    __shared__ __align__(16) unsigned short Bs[128 * 64];
    const int K = DMODEL;
    int tid  = threadIdx.x;
    int bm   = blockIdx.y * 128, bn = blockIdx.x * 128;
    int wave = tid >> 6, lane = tid & 63;
    int wm   = (wave >> 1) * 64, wn = (wave & 1) * 64;
    int lr   = lane & 15, lg = lane >> 4;

    f32x4 acc[4][4];
    f32x4 z = {0.f, 0.f, 0.f, 0.f};
#pragma unroll
    for (int i = 0; i < 4; ++i)
#pragma unroll
        for (int j = 0; j < 4; ++j) acc[i][j] = z;

    const unsigned short* Ab = A  + (size_t)bm * K;
    const unsigned short* Bb = Bw + (size_t)bn * K;

    for (int k0 = 0; k0 < K; k0 += GBK) {
        __syncthreads();
        stage_n<3, 4>(Ab + k0, As, K, wave, lane);
        stage_n<3, 4>(Bb + k0, Bs, K, wave, lane);
        __syncthreads();
#pragma unroll
        for (int kk = 0; kk < GBK; kk += 32) {
            int ck = (kk >> 3) + lg;
            bfv8 af[4], bf[4];
#pragma unroll
            for (int i = 0; i < 4; ++i)
                af[i] = *(const bfv8*)&As[(wm + i * 16 + lr) * 64 + (ck ^ (lr & 7)) * 8];
#pragma unroll
            for (int j = 0; j < 4; ++j)
                bf[j] = *(const bfv8*)&Bs[(wn + j * 16 + lr) * 64 + (ck ^ (lr & 7)) * 8];
#pragma unroll
            for (int i = 0; i < 4; ++i)
#pragma unroll
                for (int j = 0; j < 4; ++j)
                    acc[i][j] = __builtin_amdgcn_mfma_f32_16x16x32_bf16(af[i], bf[j], acc[i][j], 0, 0, 0);
        }
    }
    int lm = lr;
    int region = bn >> 11;          // block-uniform: 0=Q 1=K 2=V
    int nloc   = bn & 2047;
    if (region < 2) {
        unsigned short* C = region ? Kb : Qb;
        const float* nw = region ? knw : qnw;
        float scale = region ? 1.0f : 0.08838834764831845f;   // fold 1/sqrt(128) into Q
        float invf[4], wnw[4];
#pragma unroll
        for (int j = 0; j < 4; ++j) {
            int dd = wn + j * 16 + lm;                         // dim-in-head
            invf[j] = exp2f(-(float)(dd >> 1) * 0.20762050593046f);  // 10000^(-f/64)
            wnw[j] = nw[dd];
        }
        int sbase = (bm & (SEQ - 1)) + wm + lg * 4;            // block rows stay in one batch
        // RoPE in place (pair partner lives in lane lm^1, same j)
#pragma unroll
        for (int i = 0; i < 4; ++i)
#pragma unroll
            for (int r = 0; r < 4; ++r) {
                float sv = (float)(sbase + i * 16 + r);
#pragma unroll
                for (int j = 0; j < 4; ++j) {
                    float sn, cs;
                    __sincosf(sv * invf[j], &sn, &cs);
                    float x0 = acc[i][j][r];
                    float x1 = __shfl_xor(x0, 1);
                    acc[i][j][r] = (lm & 1) ? fmaf(x1, sn, x0 * cs)
                                            : fmaf(x0, cs, -(x1 * sn));
                }
            }
        // per-row LN over 128 dims: wave-half partials -> LDS -> combine
        float* red = (float*)As;    // 128 rows x 2 halves x 2 stats = 2 KB
        int half = wn >> 6;
        __syncthreads();            // everyone done reading As/Bs
#pragma unroll
        for (int i = 0; i < 4; ++i)
#pragma unroll
            for (int r = 0; r < 4; ++r) {
                float a0 = acc[i][0][r], a1 = acc[i][1][r], a2 = acc[i][2][r], a3 = acc[i][3][r];
                float s1 = (a0 + a1) + (a2 + a3);
                float s2 = fmaf(a0, a0, fmaf(a1, a1, fmaf(a2, a2, a3 * a3)));
#pragma unroll
                for (int msk = 1; msk <= 8; msk <<= 1) {
                    s1 += __shfl_xor(s1, msk);
                    s2 += __shfl_xor(s2, msk);
                }
                if (lm == 0) {
                    int rloc = wm + lg * 4 + i * 16 + r;
                    red[(rloc * 2 + half) * 2 + 0] = s1;
                    red[(rloc * 2 + half) * 2 + 1] = s2;
                }
            }
        __syncthreads();
#pragma unroll
        for (int i = 0; i < 4; ++i)
#pragma unroll
            for (int r = 0; r < 4; ++r) {
                int rloc = wm + lg * 4 + i * 16 + r;
                float t1 = red[(rloc * 2 + 0) * 2 + 0] + red[(rloc * 2 + 1) * 2 + 0];
                float t2 = red[(rloc * 2 + 0) * 2 + 1] + red[(rloc * 2 + 1) * 2 + 1];
                float mu  = t1 * (1.0f / 128.0f);
                float var = t2 * (1.0f / 128.0f) - mu * mu;
                float rs  = rsqrtf(var + 1e-5f) * scale;
                size_t rowoff = (size_t)(bm + rloc) * DMODEL + nloc;
#pragma unroll
                for (int j = 0; j < 4; ++j)
                    C[rowoff + wn + j * 16 + lm] = f2bf((acc[i][j][r] - mu) * rs * wnw[j]);
            }
    } else {
        int orow0 = bm + wm + lg * 4;
#pragma unroll
        for (int i = 0; i < 4; ++i) {
            int row = orow0 + i * 16;
            int bb = row >> 11, ss = row & (SEQ - 1);
#pragma unroll
            for (int j = 0; j < 4; ++j) {
                int col = nloc + wn + j * 16 + lm;
                int hh = col >> 7, dd = col & (HEADD - 1);
                ushort4 o4;
                o4.x = f2bf(acc[i][j][0]);
                o4.y = f2bf(acc[i][j][1]);
                o4.z = f2bf(acc[i][j][2]);
                o4.w = f2bf(acc[i][j][3]);
                *(ushort4*)(VT + ((size_t)((bb * NHEADS + hh) * HEADD + dd)) * SEQ + ss) = o4;
            }
        }
    }
}

// ---------- plain GEMM (fp32 out): C[M][N] = A[M][K] * Bw[N][K]^T ----------
__global__ __launch_bounds__(256) void gemm_bt(const unsigned short* __restrict__ A,
                                               const unsigned short* __restrict__ Bw,
                                               float* __restrict__ C,
                                               int M, int N, int K) {
    __shared__ __align__(16) unsigned short As[128 * 64];
    __shared__ __align__(16) unsigned short Bs[128 * 64];
    int tid  = threadIdx.x;
    int bm   = blockIdx.y * 128, bn = blockIdx.x * 128;
    int wave = tid >> 6, lane = tid & 63;
    int wm   = (wave >> 1) * 64, wn = (wave & 1) * 64;
    int lr   = lane & 15, lg = lane >> 4;

    f32x4 acc[4][4];
    f32x4 z = {0.f, 0.f, 0.f, 0.f};
#pragma unroll
    for (int i = 0; i < 4; ++i)
#pragma unroll
        for (int j = 0; j < 4; ++j) acc[i][j] = z;

    const unsigned short* Ab = A  + (size_t)bm * K;
    const unsigned short* Bb = Bw + (size_t)bn * K;

    for (int k0 = 0; k0 < K; k0 += GBK) {
        __syncthreads();
        stage_n<3, 4>(Ab + k0, As, K, wave, lane);
        stage_n<3, 4>(Bb + k0, Bs, K, wave, lane);
        __syncthreads();
#pragma unroll
        for (int kk = 0; kk < GBK; kk += 32) {
            int ck = (kk >> 3) + lg;
            bfv8 af[4], bf[4];
#pragma unroll
            for (int i = 0; i < 4; ++i)
                af[i] = *(const bfv8*)&As[(wm + i * 16 + lr) * 64 + (ck ^ (lr & 7)) * 8];
#pragma unroll
            for (int j = 0; j < 4; ++j)
                bf[j] = *(const bfv8*)&Bs[(wn + j * 16 + lr) * 64 + (ck ^ (lr & 7)) * 8];
#pragma unroll
            for (int i = 0; i < 4; ++i)
#pragma unroll
                for (int j = 0; j < 4; ++j)
                    acc[i][j] = __builtin_amdgcn_mfma_f32_16x16x32_bf16(af[i], bf[j], acc[i][j], 0, 0, 0);
        }
    }
    int orow0 = bm + wm + lg * 4;
    int ocol0 = bn + wn + lr;
#pragma unroll
    for (int i = 0; i < 4; ++i)
#pragma unroll
        for (int j = 0; j < 4; ++j)
#pragma unroll
            for (int r = 0; r < 4; ++r)
                C[(size_t)(orow0 + i * 16 + r) * N + ocol0 + j * 16] = acc[i][j][r];
}

// ---------- bf16 MFMA flash attention (sliding window), S^T compute ----------
#define AQT 64
#define AKT 64

__global__ __launch_bounds__(256) void attn_mfma(const unsigned short* __restrict__ qb,
                                                 const unsigned short* __restrict__ kb,
                                                 const unsigned short* __restrict__ vt,
                                                 unsigned short* __restrict__ ob,
                                                 const int* __restrict__ wptr) {
    __shared__ __align__(16) unsigned short Ks[64 * 128];    // K tile, swizzled, 16 KB
    __shared__ __align__(16) unsigned short Vs[128 * 64];    // V^T tile, swizzled, 16 KB
    __shared__ __align__(16) unsigned short Ps[4 * 16 * 64]; // per-wave P, swizzled, 8 KB
    int tid  = threadIdx.x;
    int wq   = tid >> 6, lane = tid & 63;
    int lm   = lane & 15, lg = lane >> 4;
    int lm7  = lm & 7;
    // XCD-grouped, heavy-first scheduling
    int gid  = blockIdx.x;
    int xcd  = gid & 7, slot = gid >> 3;
    int bh   = xcd * 4 + (slot >> 5);
    int b    = bh >> 4, h = bh & 15;
    int q0   = (31 - (slot & 31)) * AQT;
    int W    = *wptr;
    unsigned short* PsW = &Ps[wq * 1024];

    // Q B-fragments (16 queries/wave); 1/sqrt(d) pre-folded into Q
    bfv8 qa[4];
    {
        const unsigned short* qp = qb + (size_t)(b * SEQ + q0 + wq * 16 + lm) * DMODEL + h * HEADD + lg * 8;
#pragma unroll
        for (int kk = 0; kk < 4; ++kk) qa[kk] = *(const bfv8*)(qp + kk * 32);
    }

    f32x4 o[8];
    f32x4 z = {0.f, 0.f, 0.f, 0.f};
#pragma unroll
    for (int n = 0; n < 8; ++n) o[n] = z;
    float mrow = -1e30f, lrow = 0.f;   // per-lane state for query lm (replicated over lg)

    const unsigned short* kbase = kb + (size_t)(b * SEQ) * DMODEL + h * HEADD;
    const unsigned short* vbase = vt + (size_t)((b * NHEADS + h) * HEADD) * SEQ;

    int kt_lo = max(0, q0 - W) & ~(AKT - 1);
    int qi = q0 + wq * 16 + lm;

    for (int kt = kt_lo; kt < q0 + AQT; kt += AKT) {
        __syncthreads();
        stage_n<4, 4>(kbase + (size_t)kt * DMODEL, Ks, DMODEL, wq, lane);  // 64 x 128
        stage_n<3, 4>(vbase + kt, Vs, SEQ, wq, lane);                      // 128 x 64
        __syncthreads();

        // S^T = K Q^T : D[m=key][n=query], 64x16 per wave
        f32x4 s[4];
#pragma unroll
        for (int j = 0; j < 4; ++j) s[j] = z;
#pragma unroll
        for (int kk = 0; kk < 4; ++kk) {
#pragma unroll
            for (int j = 0; j < 4; ++j) {
                int ck = (kk * 4 + lg) ^ lm7;
                bfv8 af = *(const bfv8*)&Ks[(j * 16 + lm) * 128 + ck * 8];
                s[j] = __builtin_amdgcn_mfma_f32_16x16x32_bf16(af, qa[kk], s[j], 0, 0, 0);
            }
        }
        // mask only edge tiles (wave-uniform branch)
        if ((kt + 63 >= q0) || (kt < q0 + 63 - W)) {
#pragma unroll
            for (int j = 0; j < 4; ++j) {
                int kj0 = kt + j * 16 + lg * 4;
#pragma unroll
                for (int r = 0; r < 4; ++r) {
                    bool ok = (kj0 + r <= qi) && (kj0 + r >= qi - W);
                    s[j][r] = ok ? s[j][r] : -1e30f;
                }
            }
        }
        // online softmax: one query per lane, reduce across lg (masks 16, 32)
        float mx = -1e30f;
#pragma unroll
        for (int j = 0; j < 4; ++j)
#pragma unroll
            for (int r = 0; r < 4; ++r) mx = fmaxf(mx, s[j][r]);
        mx = fmaxf(mx, __shfl_xor(mx, 16));
        mx = fmaxf(mx, __shfl_xor(mx, 32));
        float mnew  = fmaxf(mrow, mx);
        float alpha = __expf(mrow - mnew);
        mrow = mnew;
        float ls = 0.f;
#pragma unroll
        for (int j = 0; j < 4; ++j) {
            float p0 = __expf(s[j][0] - mnew);
            float p1 = __expf(s[j][1] - mnew);
            float p2 = __expf(s[j][2] - mnew);
            float p3 = __expf(s[j][3] - mnew);
            ls += (p0 + p1) + (p2 + p3);
            // P^T C-layout rows = 4 consecutive keys -> one packed b64 store
            int c0 = (j * 2 + (lg >> 1)) ^ lm7;
            uint2 wv;
            wv.x = pk2(p0, p1);
            wv.y = pk2(p2, p3);
            *(uint2*)&PsW[lm * 64 + c0 * 8 + (lg & 1) * 4] = wv;
        }
        ls += __shfl_xor(ls, 16);
        ls += __shfl_xor(ls, 32);
        lrow = lrow * alpha + ls;
        // broadcast alpha from softmax layout (query=lm) to O layout (query=lg*4+r)
        float al[4];
#pragma unroll
        for (int r = 0; r < 4; ++r) al[r] = __shfl(alpha, lg * 4 + r);
#pragma unroll
        for (int n = 0; n < 8; ++n)
#pragma unroll
            for (int r = 0; r < 4; ++r) o[n][r] *= al[r];
        // O += P V : A = P (wave-private LDS, same-wave ordering), B = V^T
#pragma unroll
        for (int k2 = 0; k2 < 2; ++k2) {
            int cc = (k2 * 4 + lg) ^ lm7;
            bfv8 pa = *(const bfv8*)&PsW[lm * 64 + cc * 8];
#pragma unroll
            for (int n = 0; n < 8; ++n) {
                bfv8 vf = *(const bfv8*)&Vs[(n * 16 + lm) * 64 + cc * 8];
                o[n] = __builtin_amdgcn_mfma_f32_16x16x32_bf16(pa, vf, o[n], 0, 0, 0);
            }
        }
    }
    // epilogue
    float linv[4];
#pragma unroll
    for (int r = 0; r < 4; ++r) linv[r] = 1.0f / __shfl(lrow, lg * 4 + r);
    int qrow = q0 + wq * 16 + lg * 4;
    unsigned short* op = ob + (size_t)(b * SEQ + qrow) * DMODEL + h * HEADD + lm;
#pragma unroll
    for (int n = 0; n < 8; ++n)
#pragma unroll
        for (int r = 0; r < 4; ++r)
            op[(size_t)r * DMODEL + n * 16] = f2bf(o[n][r] * linv[r]);
}

// ---------- launch ----------
extern "C" void kernel_launch(void* const* d_in, const int* in_sizes, int n_in,
                              void* d_out, int out_size, void* d_ws, size_t ws_size,
                              hipStream_t stream) {
    const float* x   = (const float*)d_in[0];
    const float* wq  = (const float*)d_in[1];
    const float* wk  = (const float*)d_in[2];
    const float* wv  = (const float*)d_in[3];
    const float* wo  = (const float*)d_in[4];
    const float* qnw = (const float*)d_in[5];
    const float* knw = (const float*)d_in[6];
    const int*   wsz = (const int*)d_in[7];
    float* out = (float*)d_out;

    // workspace layout (~101 MB); cvt_all dst = [xb | w1 | w2 | w3 | w4] contiguous
    char* ws = (char*)d_ws;
    unsigned short* xb  = (unsigned short*)(ws);                 // 16.78 MB (x bf16; reused for attn out)
    unsigned short* w1  = (unsigned short*)(ws + 16777216);      // wq \  contiguous ->
    unsigned short* w4  = (unsigned short*)(ws + 41943040);      // wo
    unsigned short* qbf = (unsigned short*)(ws + 50331648);      // 16.78 MB bf16 Q (rope+LN+scale)
    unsigned short* kbf = (unsigned short*)(ws + 67108864);      // 16.78 MB bf16 K (rope+LN)
    unsigned short* vtb = (unsigned short*)(ws + 83886080);      // 16.78 MB bf16 V^T

    cvt_all<<<24576, 256, 0, stream>>>(x, wq, wk, wv, wo, xb);

    gemm_qkv<<<dim3(3 * DMODEL / 128, MROWS / 128), 256, 0, stream>>>(xb, w1, qbf, kbf, vtb, qnw, knw);

    attn_mfma<<<(SEQ / AQT) * NHEADS * BATCH, 256, 0, stream>>>(qbf, kbf, vtb, xb, wsz);

    gemm_bt<<<dim3(DMODEL / 128, MROWS / 128), 256, 0, stream>>>(xb, w4, out, MROWS, DMODEL, DMODEL);
}

// Round 7
// 412.859 us; speedup vs baseline: 1.1765x; 1.1765x over previous
//
#include <hip/hip_runtime.h>

// ---------- common ----------
typedef __bf16 bfv8 __attribute__((ext_vector_type(8)));
typedef float f32x4 __attribute__((ext_vector_type(4)));

#define DMODEL 2048
#define NHEADS 16
#define HEADD 128
#define SEQ 2048
#define BATCH 2
#define MROWS (BATCH * SEQ)   // 4096

__device__ __forceinline__ unsigned short f2bf(float f) {
    unsigned int x = __float_as_uint(f);
    x += 0x7fffu + ((x >> 16) & 1u);   // round-to-nearest-even
    return (unsigned short)(x >> 16);
}
__device__ __forceinline__ float bf2f(unsigned short u) {
    return __uint_as_float((unsigned int)u << 16);
}
__device__ __forceinline__ unsigned int pk2(float a, float b) {
    return (unsigned int)f2bf(a) | ((unsigned int)f2bf(b) << 16);
}

// ---------- fused fp32 -> bf16 convert for x + 4 weights (dst contiguous in ws) ----------
__global__ __launch_bounds__(256) void cvt_all(const float* __restrict__ x,
                                               const float* __restrict__ wq,
                                               const float* __restrict__ wk,
                                               const float* __restrict__ wv,
                                               const float* __restrict__ wo,
                                               unsigned short* __restrict__ dst) {
    int bid = blockIdx.x;
    const float* s;
    int off;
    if (bid < 8192)       { s = x;  off = bid; }
    else if (bid < 12288) { s = wq; off = bid - 8192; }
    else if (bid < 16384) { s = wk; off = bid - 12288; }
    else if (bid < 20480) { s = wv; off = bid - 16384; }
    else                  { s = wo; off = bid - 20480; }
    int i = off * 1024 + threadIdx.x * 4;
    float4 v = *(const float4*)(s + i);
    ushort4 o;
    o.x = f2bf(v.x); o.y = f2bf(v.y); o.z = f2bf(v.z); o.w = f2bf(v.w);
    *(ushort4*)(dst + (size_t)bid * 1024 + threadIdx.x * 4) = o;
}

// ============================================================
// global_load_lds staging into XOR-swizzled unpadded LDS.
// CPRL = log2(16B-chunks per row). Stored chunk c holds global
// chunk g = c ^ (row & 7).
// ============================================================
template <int CPRL, int ITERS>
__device__ __forceinline__ void stage_n(const unsigned short* __restrict__ gbase,
                                        unsigned short* lds, size_t strideShorts,
                                        int wave, int lane) {
#pragma unroll
    for (int i = 0; i < ITERS; ++i) {
        int L = wave * (64 * ITERS) + i * 64 + lane;
        int m = L >> CPRL, c = L & ((1 << CPRL) - 1);
        int g = c ^ (m & 7);
        const unsigned short* gp = gbase + (size_t)m * strideShorts + g * 8;
        __builtin_amdgcn_global_load_lds(
            (const __attribute__((address_space(1))) unsigned int*)gp,
            (__attribute__((address_space(3))) unsigned int*)(lds + (size_t)(wave * (64 * ITERS) + i * 64) * 8),
            16, 0, 0);
    }
}

#define GBK 64

// ---------- fused QKV GEMM: A[4096][2048] x Wcat[6144][2048]^T ----------
// N-region 0 -> Q bf16, 1 -> K bf16, 2 -> V bf16 transposed per head.
// RoPE/LN is a separate kernel: fusing it here raised VGPR 112->144 and
// halved occupancy (round-6 profile: 134 -> 253 us). Keep the epilogue thin.
__global__ __launch_bounds__(256) void gemm_qkv(const unsigned short* __restrict__ A,
                                                const unsigned short* __restrict__ Bw,
                                                unsigned short* __restrict__ Qb,
                                                unsigned short* __restrict__ Kb,
                                                unsigned short* __restrict__ VT) {
    __shared__ __align__(16) unsigned short As[128 * 64];
    __shared__ __align__(16) unsigned short Bs[128 * 64];
    const int K = DMODEL;
    int tid  = threadIdx.x;
    int bm   = blockIdx.y * 128, bn = blockIdx.x * 128;
    int wave = tid >> 6, lane = tid & 63;
    int wm   = (wave >> 1) * 64, wn = (wave & 1) * 64;
    int lr   = lane & 15, lg = lane >> 4;

    f32x4 acc[4][4];
    f32x4 z = {0.f, 0.f, 0.f, 0.f};
#pragma unroll
    for (int i = 0; i < 4; ++i)
#pragma unroll
        for (int j = 0; j < 4; ++j) acc[i][j] = z;

    const unsigned short* Ab = A  + (size_t)bm * K;
    const unsigned short* Bb = Bw + (size_t)bn * K;

    for (int k0 = 0; k0 < K; k0 += GBK) {
        __syncthreads();
        stage_n<3, 4>(Ab + k0, As, K, wave, lane);
        stage_n<3, 4>(Bb + k0, Bs, K, wave, lane);
        __syncthreads();
#pragma unroll
        for (int kk = 0; kk < GBK; kk += 32) {
            int ck = (kk >> 3) + lg;
            bfv8 af[4], bf[4];
#pragma unroll
            for (int i = 0; i < 4; ++i)
                af[i] = *(const bfv8*)&As[(wm + i * 16 + lr) * 64 + (ck ^ (lr & 7)) * 8];
#pragma unroll
            for (int j = 0; j < 4; ++j)
                bf[j] = *(const bfv8*)&Bs[(wn + j * 16 + lr) * 64 + (ck ^ (lr & 7)) * 8];
#pragma unroll
            for (int i = 0; i < 4; ++i)
#pragma unroll
                for (int j = 0; j < 4; ++j)
                    acc[i][j] = __builtin_amdgcn_mfma_f32_16x16x32_bf16(af[i], bf[j], acc[i][j], 0, 0, 0);
        }
    }
    int orow0 = bm + wm + lg * 4;
    int region = bn >> 11;          // block-uniform: 0=Q 1=K 2=V
    int nloc   = bn & 2047;
    if (region < 2) {
        unsigned short* C = region ? Kb : Qb;
#pragma unroll
        for (int i = 0; i < 4; ++i)
#pragma unroll
            for (int j = 0; j < 4; ++j)
#pragma unroll
                for (int r = 0; r < 4; ++r)
                    C[(size_t)(orow0 + i * 16 + r) * DMODEL + nloc + wn + j * 16 + lr] = f2bf(acc[i][j][r]);
    } else {
#pragma unroll
        for (int i = 0; i < 4; ++i) {
            int row = orow0 + i * 16;
            int bb = row >> 11, ss = row & (SEQ - 1);
#pragma unroll
            for (int j = 0; j < 4; ++j) {
                int col = nloc + wn + j * 16 + lr;
                int hh = col >> 7, dd = col & (HEADD - 1);
                ushort4 o4;
                o4.x = f2bf(acc[i][j][0]);
                o4.y = f2bf(acc[i][j][1]);
                o4.z = f2bf(acc[i][j][2]);
                o4.w = f2bf(acc[i][j][3]);
                *(ushort4*)(VT + ((size_t)((bb * NHEADS + hh) * HEADD + dd)) * SEQ + ss) = o4;
            }
        }
    }
}

// ---------- plain GEMM (fp32 out): C[M][N] = A[M][K] * Bw[N][K]^T ----------
__global__ __launch_bounds__(256) void gemm_bt(const unsigned short* __restrict__ A,
                                               const unsigned short* __restrict__ Bw,
                                               float* __restrict__ C,
                                               int M, int N, int K) {
    __shared__ __align__(16) unsigned short As[128 * 64];
    __shared__ __align__(16) unsigned short Bs[128 * 64];
    int tid  = threadIdx.x;
    int bm   = blockIdx.y * 128, bn = blockIdx.x * 128;
    int wave = tid >> 6, lane = tid & 63;
    int wm   = (wave >> 1) * 64, wn = (wave & 1) * 64;
    int lr   = lane & 15, lg = lane >> 4;

    f32x4 acc[4][4];
    f32x4 z = {0.f, 0.f, 0.f, 0.f};
#pragma unroll
    for (int i = 0; i < 4; ++i)
#pragma unroll
        for (int j = 0; j < 4; ++j) acc[i][j] = z;

    const unsigned short* Ab = A  + (size_t)bm * K;
    const unsigned short* Bb = Bw + (size_t)bn * K;

    for (int k0 = 0; k0 < K; k0 += GBK) {
        __syncthreads();
        stage_n<3, 4>(Ab + k0, As, K, wave, lane);
        stage_n<3, 4>(Bb + k0, Bs, K, wave, lane);
        __syncthreads();
#pragma unroll
        for (int kk = 0; kk < GBK; kk += 32) {
            int ck = (kk >> 3) + lg;
            bfv8 af[4], bf[4];
#pragma unroll
            for (int i = 0; i < 4; ++i)
                af[i] = *(const bfv8*)&As[(wm + i * 16 + lr) * 64 + (ck ^ (lr & 7)) * 8];
#pragma unroll
            for (int j = 0; j < 4; ++j)
                bf[j] = *(const bfv8*)&Bs[(wn + j * 16 + lr) * 64 + (ck ^ (lr & 7)) * 8];
#pragma unroll
            for (int i = 0; i < 4; ++i)
#pragma unroll
                for (int j = 0; j < 4; ++j)
                    acc[i][j] = __builtin_amdgcn_mfma_f32_16x16x32_bf16(af[i], bf[j], acc[i][j], 0, 0, 0);
        }
    }
    int orow0 = bm + wm + lg * 4;
    int ocol0 = bn + wn + lr;
#pragma unroll
    for (int i = 0; i < 4; ++i)
#pragma unroll
        for (int j = 0; j < 4; ++j)
#pragma unroll
            for (int r = 0; r < 4; ++r)
                C[(size_t)(orow0 + i * 16 + r) * N + ocol0 + j * 16] = acc[i][j][r];
}

// ---------- RoPE + per-head LayerNorm, in-place on bf16; Q pre-scaled ----------
__global__ __launch_bounds__(256) void rope_ln_ip(unsigned short* __restrict__ qt,
                                                  unsigned short* __restrict__ kt,
                                                  const float* __restrict__ qw,
                                                  const float* __restrict__ kw) {
    int which = blockIdx.y;
    unsigned short* t = which ? kt : qt;
    const float* w = which ? kw : qw;
    float scale = which ? 1.0f : 0.08838834764831845f;   // fold 1/sqrt(128) into Q
    int gr   = blockIdx.x * 4 + (threadIdx.x >> 6);
    int lane = threadIdx.x & 63;
    int m = gr >> 4;
    int h = gr & 15;
    int s = m & (SEQ - 1);
    unsigned short* p = t + (size_t)m * DMODEL + h * HEADD + lane * 2;
    ushort2 xv = *(const ushort2*)p;
    float x0 = bf2f(xv.x), x1 = bf2f(xv.y);
    float inv = powf(10000.0f, -(float)lane * (1.0f / 64.0f));
    float ang = (float)s * inv;
    float sn, c;
    sincosf(ang, &sn, &c);
    float y0 = x0 * c - x1 * sn;
    float y1 = x0 * sn + x1 * c;
    float sum = y0 + y1;
    float sq  = y0 * y0 + y1 * y1;
#pragma unroll
    for (int o = 32; o >= 1; o >>= 1) {
        sum += __shfl_xor(sum, o);
        sq  += __shfl_xor(sq, o);
    }
    float mu  = sum * (1.0f / 128.0f);
    float var = sq * (1.0f / 128.0f) - mu * mu;
    float rs  = rsqrtf(var + 1e-5f) * scale;
    float2 wv = *(const float2*)(w + lane * 2);
    ushort2 ov;
    ov.x = f2bf((y0 - mu) * rs * wv.x);
    ov.y = f2bf((y1 - mu) * rs * wv.y);
    *(ushort2*)p = ov;
}

// ---------- bf16 MFMA flash attention (sliding window), S^T compute ----------
#define AQT 64
#define AKT 64

__global__ __launch_bounds__(256) void attn_mfma(const unsigned short* __restrict__ qb,
                                                 const unsigned short* __restrict__ kb,
                                                 const unsigned short* __restrict__ vt,
                                                 unsigned short* __restrict__ ob,
                                                 const int* __restrict__ wptr) {
    __shared__ __align__(16) unsigned short Ks[64 * 128];    // K tile, swizzled, 16 KB
    __shared__ __align__(16) unsigned short Vs[128 * 64];    // V^T tile, swizzled, 16 KB
    __shared__ __align__(16) unsigned short Ps[4 * 16 * 64]; // per-wave P, swizzled, 8 KB
    int tid  = threadIdx.x;
    int wq   = tid >> 6, lane = tid & 63;
    int lm   = lane & 15, lg = lane >> 4;
    int lm7  = lm & 7;
    // XCD-grouped, heavy-first scheduling
    int gid  = blockIdx.x;
    int xcd  = gid & 7, slot = gid >> 3;
    int bh   = xcd * 4 + (slot >> 5);
    int b    = bh >> 4, h = bh & 15;
    int q0   = (31 - (slot & 31)) * AQT;
    int W    = *wptr;
    unsigned short* PsW = &Ps[wq * 1024];

    // Q B-fragments (16 queries/wave); 1/sqrt(d) pre-folded into Q
    bfv8 qa[4];
    {
        const unsigned short* qp = qb + (size_t)(b * SEQ + q0 + wq * 16 + lm) * DMODEL + h * HEADD + lg * 8;
#pragma unroll
        for (int kk = 0; kk < 4; ++kk) qa[kk] = *(const bfv8*)(qp + kk * 32);
    }

    f32x4 o[8];
    f32x4 z = {0.f, 0.f, 0.f, 0.f};
#pragma unroll
    for (int n = 0; n < 8; ++n) o[n] = z;
    float mrow = -1e30f, lrow = 0.f;   // per-lane state for query lm (replicated over lg)

    const unsigned short* kbase = kb + (size_t)(b * SEQ) * DMODEL + h * HEADD;
    const unsigned short* vbase = vt + (size_t)((b * NHEADS + h) * HEADD) * SEQ;

    int kt_lo = max(0, q0 - W) & ~(AKT - 1);
    int qi = q0 + wq * 16 + lm;

    for (int kt = kt_lo; kt < q0 + AQT; kt += AKT) {
        __syncthreads();
        stage_n<4, 4>(kbase + (size_t)kt * DMODEL, Ks, DMODEL, wq, lane);  // 64 x 128
        stage_n<3, 4>(vbase + kt, Vs, SEQ, wq, lane);                      // 128 x 64
        __syncthreads();

        // S^T = K Q^T : D[m=key][n=query], 64x16 per wave
        f32x4 s[4];
#pragma unroll
        for (int j = 0; j < 4; ++j) s[j] = z;
#pragma unroll
        for (int kk = 0; kk < 4; ++kk) {
#pragma unroll
            for (int j = 0; j < 4; ++j) {
                int ck = (kk * 4 + lg) ^ lm7;
                bfv8 af = *(const bfv8*)&Ks[(j * 16 + lm) * 128 + ck * 8];
                s[j] = __builtin_amdgcn_mfma_f32_16x16x32_bf16(af, qa[kk], s[j], 0, 0, 0);
            }
        }
        // mask only edge tiles (wave-uniform branch)
        if ((kt + 63 >= q0) || (kt < q0 + 63 - W)) {
#pragma unroll
            for (int j = 0; j < 4; ++j) {
                int kj0 = kt + j * 16 + lg * 4;
#pragma unroll
                for (int r = 0; r < 4; ++r) {
                    bool ok = (kj0 + r <= qi) && (kj0 + r >= qi - W);
                    s[j][r] = ok ? s[j][r] : -1e30f;
                }
            }
        }
        // online softmax: one query per lane, reduce across lg (masks 16, 32)
        float mx = -1e30f;
#pragma unroll
        for (int j = 0; j < 4; ++j)
#pragma unroll
            for (int r = 0; r < 4; ++r) mx = fmaxf(mx, s[j][r]);
        mx = fmaxf(mx, __shfl_xor(mx, 16));
        mx = fmaxf(mx, __shfl_xor(mx, 32));
        float mnew  = fmaxf(mrow, mx);
        float alpha = __expf(mrow - mnew);
        mrow = mnew;
        float ls = 0.f;
#pragma unroll
        for (int j = 0; j < 4; ++j) {
            float p0 = __expf(s[j][0] - mnew);
            float p1 = __expf(s[j][1] - mnew);
            float p2 = __expf(s[j][2] - mnew);
            float p3 = __expf(s[j][3] - mnew);
            ls += (p0 + p1) + (p2 + p3);
            // P^T C-layout rows = 4 consecutive keys -> one packed b64 store
            int c0 = (j * 2 + (lg >> 1)) ^ lm7;
            uint2 wv;
            wv.x = pk2(p0, p1);
            wv.y = pk2(p2, p3);
            *(uint2*)&PsW[lm * 64 + c0 * 8 + (lg & 1) * 4] = wv;
        }
        ls += __shfl_xor(ls, 16);
        ls += __shfl_xor(ls, 32);
        lrow = lrow * alpha + ls;
        // broadcast alpha from softmax layout (query=lm) to O layout (query=lg*4+r)
        float al[4];
#pragma unroll
        for (int r = 0; r < 4; ++r) al[r] = __shfl(alpha, lg * 4 + r);
#pragma unroll
        for (int n = 0; n < 8; ++n)
#pragma unroll
            for (int r = 0; r < 4; ++r) o[n][r] *= al[r];
        // O += P V : A = P (wave-private LDS, same-wave ordering), B = V^T
#pragma unroll
        for (int k2 = 0; k2 < 2; ++k2) {
            int cc = (k2 * 4 + lg) ^ lm7;
            bfv8 pa = *(const bfv8*)&PsW[lm * 64 + cc * 8];
#pragma unroll
            for (int n = 0; n < 8; ++n) {
                bfv8 vf = *(const bfv8*)&Vs[(n * 16 + lm) * 64 + cc * 8];
                o[n] = __builtin_amdgcn_mfma_f32_16x16x32_bf16(pa, vf, o[n], 0, 0, 0);
            }
        }
    }
    // epilogue
    float linv[4];
#pragma unroll
    for (int r = 0; r < 4; ++r) linv[r] = 1.0f / __shfl(lrow, lg * 4 + r);
    int qrow = q0 + wq * 16 + lg * 4;
    unsigned short* op = ob + (size_t)(b * SEQ + qrow) * DMODEL + h * HEADD + lm;
#pragma unroll
    for (int n = 0; n < 8; ++n)
#pragma unroll
        for (int r = 0; r < 4; ++r)
            op[(size_t)r * DMODEL + n * 16] = f2bf(o[n][r] * linv[r]);
}

// ---------- launch ----------
extern "C" void kernel_launch(void* const* d_in, const int* in_sizes, int n_in,
                              void* d_out, int out_size, void* d_ws, size_t ws_size,
                              hipStream_t stream) {
    const float* x   = (const float*)d_in[0];
    const float* wq  = (const float*)d_in[1];
    const float* wk  = (const float*)d_in[2];
    const float* wv  = (const float*)d_in[3];
    const float* wo  = (const float*)d_in[4];
    const float* qnw = (const float*)d_in[5];
    const float* knw = (const float*)d_in[6];
    const int*   wsz = (const int*)d_in[7];
    float* out = (float*)d_out;

    // workspace layout (~101 MB); cvt_all dst = [xb | w1 | w2 | w3 | w4] contiguous
    char* ws = (char*)d_ws;
    unsigned short* xb  = (unsigned short*)(ws);                 // 16.78 MB (x bf16; reused for attn out)
    unsigned short* w1  = (unsigned short*)(ws + 16777216);      // wq \  contiguous ->
    unsigned short* w4  = (unsigned short*)(ws + 41943040);      // wo
    unsigned short* qbf = (unsigned short*)(ws + 50331648);      // 16.78 MB bf16 Q
    unsigned short* kbf = (unsigned short*)(ws + 67108864);      // 16.78 MB bf16 K
    unsigned short* vtb = (unsigned short*)(ws + 83886080);      // 16.78 MB bf16 V^T

    cvt_all<<<24576, 256, 0, stream>>>(x, wq, wk, wv, wo, xb);

    gemm_qkv<<<dim3(3 * DMODEL / 128, MROWS / 128), 256, 0, stream>>>(xb, w1, qbf, kbf, vtb);

    rope_ln_ip<<<dim3(MROWS * NHEADS / 4, 2), 256, 0, stream>>>(qbf, kbf, qnw, knw);

    attn_mfma<<<(SEQ / AQT) * NHEADS * BATCH, 256, 0, stream>>>(qbf, kbf, vtb, xb, wsz);

    gemm_bt<<<dim3(DMODEL / 128, MROWS / 128), 256, 0, stream>>>(xb, w4, out, MROWS, DMODEL, DMODEL);
}